// Round 4
// baseline (314.746 us; speedup 1.0000x reference)
//
#include <hip/hip_runtime.h>
#include <math.h>

#define Bn 128
#define Sn 200
#define NC3n 4000

__device__ __forceinline__ float sigmf(float x) { return 1.f / (1.f + __expf(-x)); }
__device__ __forceinline__ float rlane(float v, int k) {
    return __int_as_float(__builtin_amdgcn_readlane(__float_as_int(v), k));
}

// ============ kernel 1: per-row C3 chain values -> ws_val[b*Sn + t] ============
__global__ __launch_bounds__(256) void chain_kernel(
    const int* __restrict__ c3_seq, const int* __restrict__ d_seq,
    const int* __restrict__ r_seq, const float* __restrict__ v_c3,
    const float* __restrict__ D_w, const float* __restrict__ v_d,
    const float* __restrict__ R_w,
    const float* __restrict__ l2_w1, const float* __restrict__ l2_b1,
    const float* __restrict__ l2_w2, const float* __restrict__ l2_b2,
    float* __restrict__ ws_val)
{
    __shared__ float gam_lds[Sn];
    __shared__ int   r_lds[Sn];
    __shared__ int   c3_lds[Sn];
    __shared__ float val_lds[Sn];
    __shared__ int   succ_lds[Sn];
    __shared__ int   root_lds[Sn];
    __shared__ float wsA[64], wsB[64], wsC0[64], wsC1[64], wsW2[64];
    __shared__ float l2b2_sh;

    const int tid = threadIdx.x;
    const int b   = blockIdx.x;

    if (tid < Sn) {
        gam_lds[tid] = D_w[d_seq[b*Sn + tid]];
        r_lds[tid]   = r_seq[b*Sn + tid];
        c3_lds[tid]  = c3_seq[b*Sn + tid];
    }
    // collapsed mlp2 constants: A = l2_w1[:, :64]@v_c3, B = @v_d, C_r = @R_w[r] + l2_b1
    if (tid < 64) {
        const float* row = l2_w1 + (size_t)tid * 192;
        float a2=0.f, b2=0.f, c0=0.f, c1=0.f;
        for (int k = 0; k < 64; ++k) {
            a2 += row[k]       * v_c3[k];
            b2 += row[64 + k]  * v_d[k];
            c0 += row[128 + k] * R_w[k];
            c1 += row[128 + k] * R_w[64 + k];
        }
        wsA[tid]  = a2;
        wsB[tid]  = b2;
        wsC0[tid] = c0 + l2_b1[tid];
        wsC1[tid] = c1 + l2_b1[tid];
        wsW2[tid] = l2_w2[tid];
    }
    if (tid == 0) l2b2_sh = l2_b2[0];
    __syncthreads();
    // successor / root links per timestep (same c3 index)
    if (tid < Sn) {
        int c = c3_lds[tid];
        int s = -1;
        for (int u = tid + 1; u < Sn; ++u)
            if (c3_lds[u] == c) { s = u; break; }
        succ_lds[tid] = s;
        int rt = 1;
        for (int u = 0; u < tid; ++u)
            if (c3_lds[u] == c) { rt = 0; break; }
        root_lds[tid] = rt;
    }
    __syncthreads();
    // walk each dependency chain with a 16-lane group (16 groups/block)
    {
        const int g  = tid >> 4;
        const int l  = tid & 15;
        const int j0 = l * 4;
        float A0=wsA[j0],  A1=wsA[j0+1],  A2=wsA[j0+2],  A3=wsA[j0+3];
        float B0=wsB[j0],  B1=wsB[j0+1],  B2=wsB[j0+2],  B3=wsB[j0+3];
        float C00=wsC0[j0],C01=wsC0[j0+1],C02=wsC0[j0+2],C03=wsC0[j0+3];
        float C10=wsC1[j0],C11=wsC1[j0+1],C12=wsC1[j0+2],C13=wsC1[j0+3];
        float W0=wsW2[j0], W1=wsW2[j0+1], W2v=wsW2[j0+2],W3=wsW2[j0+3];
        float l2b2 = l2b2_sh;
        for (int t0 = g; t0 < Sn; t0 += 16) {
            if (!root_lds[t0]) continue;
            float beta = 0.f;
            int t = t0;
            while (t >= 0) {
                float gam = gam_lds[t];
                int   r   = r_lds[t];
                float s = W0*fmaxf(A0*beta + B0*gam + (r ? C10 : C00), 0.f)
                        + W1*fmaxf(A1*beta + B1*gam + (r ? C11 : C01), 0.f)
                        + W2v*fmaxf(A2*beta + B2*gam + (r ? C12 : C02), 0.f)
                        + W3*fmaxf(A3*beta + B3*gam + (r ? C13 : C03), 0.f);
                s += __shfl_xor(s, 1, 16);
                s += __shfl_xor(s, 2, 16);
                s += __shfl_xor(s, 4, 16);
                s += __shfl_xor(s, 8, 16);
                beta = s + l2b2;            // uniform across the 16 lanes
                if (l == 0) val_lds[t] = beta;
                t = succ_lds[t];
            }
        }
    }
    __syncthreads();
    if (tid < Sn) ws_val[b*Sn + tid] = val_lds[tid];
}

// ============ kernel 2: streaming forward-fill of out_c3 (pure stores) ============
__global__ __launch_bounds__(256) void fill_kernel(
    const int* __restrict__ c3_seq, const float* __restrict__ ws_val,
    float* __restrict__ out_c3)
{
    __shared__ int   c3_lds[Sn];
    __shared__ float val_lds[Sn];
    const int tid   = threadIdx.x;
    const int fb    = blockIdx.x;
    const int b     = fb >> 2;
    const int chunk = fb & 3;
    if (tid < Sn) {
        c3_lds[tid]  = c3_seq[b*Sn + tid];
        val_lds[tid] = ws_val[b*Sn + tid];
    }
    __syncthreads();
    if (tid < 250) {
        const int col = chunk * 1000 + tid * 4;
        float4 curv = make_float4(0.f, 0.f, 0.f, 0.f);
        float* outp = out_c3 + (size_t)b * Sn * NC3n + col;
        for (int t = 0; t < Sn; ++t) {
            int d = c3_lds[t] - col;
            if ((unsigned)d < 4u) {
                float v = val_lds[t];
                curv.x = (d == 0) ? v : curv.x;
                curv.y = (d == 1) ? v : curv.y;
                curv.z = (d == 2) ? v : curv.z;
                curv.w = (d == 3) ? v : curv.w;
            }
            *(float4*)outp = curv;
            outp += NC3n;
        }
    }
}

// ============ kernel 3: GRU + mlp1 + alpha, one row per block ============
__global__ __launch_bounds__(256, 1) void gru_kernel(
    const int* __restrict__ d_seq, const int* __restrict__ r_seq,
    const float* __restrict__ D_w, const float* __restrict__ v_d,
    const float* __restrict__ R_w, const float* __restrict__ W_ih,
    const float* __restrict__ W_hh, const float* __restrict__ b_ih,
    const float* __restrict__ b_hh,
    const float* __restrict__ l1_w1, const float* __restrict__ l1_b1,
    const float* __restrict__ l1_w2, const float* __restrict__ l1_b2,
    float* __restrict__ out_alpha, float* __restrict__ out_h)
{
    __shared__ float u_lds[192], w0_lds[192], w1_lds[192];
    __shared__ float hg[2][192];
    __shared__ float gam_lds[Sn];
    __shared__ int   r_lds[Sn];

    const int tid = threadIdx.x;
    const int b   = blockIdx.x;

    if (tid < Sn) {
        gam_lds[tid] = D_w[d_seq[b * Sn + tid]];
        r_lds[tid]   = r_seq[b * Sn + tid];
    }
    // fold the xg precompute: u = W_ih[:, :64]@v_d ; w0/w1 = W_ih[:, 64:]@R_w[r] + b_ih
    if (tid < 192) {
        const float4* row = (const float4*)(W_ih + tid * 128);
        const float4* vd4 = (const float4*)v_d;
        const float4* r04 = (const float4*)R_w;
        const float4* r14 = (const float4*)(R_w + 64);
        float u = 0.f, w0 = 0.f, w1 = 0.f;
        #pragma unroll 4
        for (int k = 0; k < 16; ++k) {
            float4 a  = row[k];
            float4 bb = row[16 + k];
            float4 vd = vd4[k], r0 = r04[k], r1 = r14[k];
            u  += a.x*vd.x + a.y*vd.y + a.z*vd.z + a.w*vd.w;
            w0 += bb.x*r0.x + bb.y*r0.y + bb.z*r0.z + bb.w*r0.w;
            w1 += bb.x*r1.x + bb.y*r1.y + bb.z*r1.z + bb.w*r1.w;
        }
        u_lds[tid]  = u;
        w0_lds[tid] = w0 + b_ih[tid];
        w1_lds[tid] = w1 + b_ih[tid];
    }
    // unified weight row: tid>=64 -> W_hh row (tid-64); tid<64 -> l1_w1 row tid
    float w[64];
    {
        const float* src = (tid >= 64) ? (W_hh + (size_t)(tid - 64) * 64)
                                       : (l1_w1 + (size_t)tid * 64);
        const float4* s4 = (const float4*)src;
        #pragma unroll
        for (int k = 0; k < 16; ++k) {
            float4 v = s4[k];
            w[4*k+0]=v.x; w[4*k+1]=v.y; w[4*k+2]=v.z; w[4*k+3]=v.w;
        }
    }
    float bhh = 0.f, l1b = 0.f, l1w2v = 0.f;
    if (tid >= 64) {
        bhh = b_hh[tid - 64];
        hg[0][tid - 64] = bhh;          // h0 = 0 -> hg(t=0) = b_hh
    } else {
        l1b = l1_b1[tid]; l1w2v = l1_w2[tid];
    }
    const float l1b2c = l1_b2[0];
    __syncthreads();

    const int j = tid & 63;
    const float uj  = u_lds[j],  u1  = u_lds[64+j],  u2  = u_lds[128+j];
    const float w00 = w0_lds[j], w01 = w0_lds[64+j], w02 = w0_lds[128+j];
    const float w10 = w1_lds[j], w11 = w1_lds[64+j], w12 = w1_lds[128+j];
    float vh = 0.f, alpha = 0.f;
    int cur = 0;
    float* outh_p = out_h + (size_t)b * Sn * 64 + j;

    for (int t = 0; t < Sn; ++t) {
        float gam = gam_lds[t];
        int   r   = r_lds[t];
        // gates (computed redundantly by every thread; h[j] stays in vh)
        float hr = hg[cur][j], hz = hg[cur][64+j], hn = hg[cur][128+j];
        float rg = sigmf(fmaf(gam, uj, (r ? w10 : w00)) + hr);
        float zg = sigmf(fmaf(gam, u1, (r ? w11 : w01)) + hz);
        float e2 = __expf(2.f * (fmaf(gam, u2, (r ? w12 : w02)) + rg*hn));
        float ng = (e2 - 1.f) / (e2 + 1.f);   // tanh
        vh = (1.f - zg)*ng + zg*vh;
        // unified dot(w, h) via readlane broadcast (no LDS pipe)
        float a0=0.f, a1=0.f, a2=0.f, a3=0.f;
        #pragma unroll
        for (int k = 0; k < 64; k += 4) {
            a0 = fmaf(rlane(vh, k+0), w[k+0], a0);
            a1 = fmaf(rlane(vh, k+1), w[k+1], a1);
            a2 = fmaf(rlane(vh, k+2), w[k+2], a2);
            a3 = fmaf(rlane(vh, k+3), w[k+3], a3);
        }
        float dot = (a0 + a1) + (a2 + a3);
        if (tid >= 64) {
            hg[cur ^ 1][tid - 64] = bhh + dot;   // hg for t+1 (other buffer)
        } else {
            float p = fmaxf(dot + l1b, 0.f) * l1w2v;
            #pragma unroll
            for (int off = 32; off > 0; off >>= 1)
                p += __shfl_xor(p, off);
            outh_p[0] = vh; outh_p += 64;
            if (tid == 0) {
                float an = p + l1b2c;
                bool cond = (alpha - gam) >= 0.f;
                alpha = (r == 1) ? (cond ? an : alpha) : (cond ? alpha : an);
                out_alpha[b*Sn + t] = alpha;
            }
        }
        __syncthreads();
        cur ^= 1;
    }
}

extern "C" void kernel_launch(void* const* d_in, const int* in_sizes, int n_in,
                              void* d_out, int out_size, void* d_ws, size_t ws_size,
                              hipStream_t stream)
{
    const int*   c3_seq = (const int*)  d_in[0];
    const int*   d_seq  = (const int*)  d_in[1];
    const int*   r_seq  = (const int*)  d_in[2];
    const float* v_c3   = (const float*)d_in[3];
    const float* D_w    = (const float*)d_in[4];
    const float* v_d    = (const float*)d_in[5];
    const float* R_w    = (const float*)d_in[6];
    const float* W_ih   = (const float*)d_in[7];
    const float* W_hh   = (const float*)d_in[8];
    const float* b_ih   = (const float*)d_in[9];
    const float* b_hh   = (const float*)d_in[10];
    const float* l1_w1  = (const float*)d_in[11];
    const float* l1_b1  = (const float*)d_in[12];
    const float* l1_w2  = (const float*)d_in[13];
    const float* l1_b2  = (const float*)d_in[14];
    const float* l2_w1  = (const float*)d_in[15];
    const float* l2_b1  = (const float*)d_in[16];
    const float* l2_w2  = (const float*)d_in[17];
    const float* l2_b2  = (const float*)d_in[18];

    float* ws_val    = (float*)d_ws;                 // [Bn][Sn]
    float* out_alpha = (float*)d_out;
    float* out_h     = out_alpha + Bn*Sn;
    float* out_c3    = out_h + (size_t)Bn*Sn*64;

    chain_kernel<<<Bn, 256, 0, stream>>>(c3_seq, d_seq, r_seq, v_c3, D_w, v_d, R_w,
                                         l2_w1, l2_b1, l2_w2, l2_b2, ws_val);
    fill_kernel<<<Bn * 4, 256, 0, stream>>>(c3_seq, ws_val, out_c3);
    gru_kernel<<<Bn, 256, 0, stream>>>(d_seq, r_seq, D_w, v_d, R_w, W_ih, W_hh,
                                       b_ih, b_hh, l1_w1, l1_b1, l1_w2, l1_b2,
                                       out_alpha, out_h);
}

// Round 5
// 211.385 us; speedup vs baseline: 1.4890x; 1.4890x over previous
//
#include <hip/hip_runtime.h>
#include <math.h>

#define Bn 128
#define Sn 200
#define NC3n 4000
#define GRU_BLOCKS 128
#define FILL_BLOCKS (Bn * 4)

__device__ __forceinline__ float sigmf(float x) { return 1.f / (1.f + __expf(-x)); }
__device__ __forceinline__ float rlane(float v, int k) {
    return __int_as_float(__builtin_amdgcn_readlane(__float_as_int(v), k));
}

__global__ __launch_bounds__(256) void fused_kernel(
    const int* __restrict__ c3_seq, const int* __restrict__ d_seq,
    const int* __restrict__ r_seq, const float* __restrict__ v_c3,
    const float* __restrict__ D_w, const float* __restrict__ v_d,
    const float* __restrict__ R_w, const float* __restrict__ W_ih,
    const float* __restrict__ W_hh, const float* __restrict__ b_ih,
    const float* __restrict__ b_hh,
    const float* __restrict__ l1_w1, const float* __restrict__ l1_b1,
    const float* __restrict__ l1_w2, const float* __restrict__ l1_b2,
    const float* __restrict__ l2_w1, const float* __restrict__ l2_b1,
    const float* __restrict__ l2_w2, const float* __restrict__ l2_b2,
    float* __restrict__ out_alpha, float* __restrict__ out_h,
    float* __restrict__ out_c3)
{
    __shared__ float gam_lds[Sn];
    __shared__ int   r_lds[Sn];
    // GRU path
    __shared__ float l1T[64 * 64];      // l1_w1 transposed: l1T[k*64+j] = l1_w1[j][k]
    // Fill path
    __shared__ int   c3_lds[Sn];
    __shared__ float val_lds[Sn];
    __shared__ int   succ_lds[Sn];
    __shared__ int   root_lds[Sn];
    __shared__ float wsA[64], wsB[64], wsC0[64], wsC1[64], wsW2[64];
    __shared__ float l2b2_sh;

    const int tid = threadIdx.x;
    const int bid = blockIdx.x;

    if (bid < GRU_BLOCKS) {
        // ======== single-wave GRU + mlp1 + alpha : one batch row, NO barriers ========
        if (tid >= 64) return;          // waves 1-3 exit immediately
        const int b = bid;
        const int j = tid;              // lane owns h[j]

        for (int i = j; i < Sn; i += 64) {
            gam_lds[i] = D_w[d_seq[b * Sn + i]];
            r_lds[i]   = r_seq[b * Sn + i];
        }
        // l1_w1 row j -> transposed LDS (conflict-free column reads later)
        {
            const float4* lr = (const float4*)(l1_w1 + (size_t)j * 64);
            #pragma unroll
            for (int k4 = 0; k4 < 16; ++k4) {
                float4 v = lr[k4];
                l1T[(4*k4+0)*64 + j] = v.x;
                l1T[(4*k4+1)*64 + j] = v.y;
                l1T[(4*k4+2)*64 + j] = v.z;
                l1T[(4*k4+3)*64 + j] = v.w;
            }
        }
        // W_hh rows j (r-gate), 64+j (z), 128+j (n) in registers
        float wr[64], wz[64], wn[64];
        {
            const float4* r0 = (const float4*)(W_hh + (size_t)j * 64);
            const float4* r1 = (const float4*)(W_hh + (size_t)(64 + j) * 64);
            const float4* r2 = (const float4*)(W_hh + (size_t)(128 + j) * 64);
            #pragma unroll
            for (int k = 0; k < 16; ++k) {
                float4 a = r0[k], c = r1[k], d = r2[k];
                wr[4*k+0]=a.x; wr[4*k+1]=a.y; wr[4*k+2]=a.z; wr[4*k+3]=a.w;
                wz[4*k+0]=c.x; wz[4*k+1]=c.y; wz[4*k+2]=c.z; wz[4*k+3]=c.w;
                wn[4*k+0]=d.x; wn[4*k+1]=d.y; wn[4*k+2]=d.z; wn[4*k+3]=d.w;
            }
        }
        // fold xg: per gate-row rho: u=W_ih[rho,:64]@v_d ; w0/w1=W_ih[rho,64:]@R_w[r]+b_ih
        float uu[3], ww0[3], ww1[3];
        #pragma unroll
        for (int g = 0; g < 3; ++g) {
            const int rho = g * 64 + j;
            const float4* rp  = (const float4*)(W_ih + (size_t)rho * 128);
            const float4* vd4 = (const float4*)v_d;
            const float4* r04 = (const float4*)R_w;
            const float4* r14 = (const float4*)(R_w + 64);
            float u = 0.f, w0 = 0.f, w1 = 0.f;
            #pragma unroll 4
            for (int k = 0; k < 16; ++k) {
                float4 a  = rp[k];
                float4 bb = rp[16 + k];
                float4 vd = vd4[k], q0 = r04[k], q1 = r14[k];
                u  += a.x*vd.x + a.y*vd.y + a.z*vd.z + a.w*vd.w;
                w0 += bb.x*q0.x + bb.y*q0.y + bb.z*q0.z + bb.w*q0.w;
                w1 += bb.x*q1.x + bb.y*q1.y + bb.z*q1.z + bb.w*q1.w;
            }
            float bih = b_ih[rho];
            uu[g] = u; ww0[g] = w0 + bih; ww1[g] = w1 + bih;
        }
        const float bhr = b_hh[j], bhz = b_hh[64 + j], bhn = b_hh[128 + j];
        const float l1b = l1_b1[j], l1w2v = l1_w2[j], l1b2c = l1_b2[0];

        float vh = 0.f, alpha = 0.f;
        float hgr = bhr, hgz = bhz, hgn = bhn;   // W_hh@h0 + b_hh with h0=0
        float* outh_p = out_h + (size_t)b * Sn * 64 + j;

        for (int t = 0; t < Sn; ++t) {
            float gam = gam_lds[t];
            int   r   = r_lds[t];
            float xr = fmaf(gam, uu[0], r ? ww1[0] : ww0[0]);
            float xz = fmaf(gam, uu[1], r ? ww1[1] : ww0[1]);
            float xn = fmaf(gam, uu[2], r ? ww1[2] : ww0[2]);
            float rg = sigmf(xr + hgr);
            float zg = sigmf(xz + hgz);
            float e2 = __expf(2.f * (xn + rg * hgn));
            float ng = (e2 - 1.f) / (e2 + 1.f);          // tanh
            vh = (1.f - zg) * ng + zg * vh;
            outh_p[0] = vh; outh_p += 64;
            // four dots via readlane broadcast, 4 accumulators each (chain depth 16)
            float ar0=0,ar1=0,ar2=0,ar3=0, az0=0,az1=0,az2=0,az3=0;
            float an0=0,an1=0,an2=0,an3=0, am0=0,am1=0,am2=0,am3=0;
            #pragma unroll
            for (int k = 0; k < 64; k += 4) {
                float s0 = rlane(vh, k+0), s1 = rlane(vh, k+1);
                float s2 = rlane(vh, k+2), s3 = rlane(vh, k+3);
                ar0 = fmaf(wr[k+0], s0, ar0); ar1 = fmaf(wr[k+1], s1, ar1);
                ar2 = fmaf(wr[k+2], s2, ar2); ar3 = fmaf(wr[k+3], s3, ar3);
                az0 = fmaf(wz[k+0], s0, az0); az1 = fmaf(wz[k+1], s1, az1);
                az2 = fmaf(wz[k+2], s2, az2); az3 = fmaf(wz[k+3], s3, az3);
                an0 = fmaf(wn[k+0], s0, an0); an1 = fmaf(wn[k+1], s1, an1);
                an2 = fmaf(wn[k+2], s2, an2); an3 = fmaf(wn[k+3], s3, an3);
                am0 = fmaf(l1T[(k+0)*64 + j], s0, am0);
                am1 = fmaf(l1T[(k+1)*64 + j], s1, am1);
                am2 = fmaf(l1T[(k+2)*64 + j], s2, am2);
                am3 = fmaf(l1T[(k+3)*64 + j], s3, am3);
            }
            hgr = bhr + ((ar0+ar1)+(ar2+ar3));
            hgz = bhz + ((az0+az1)+(az2+az3));
            hgn = bhn + ((an0+an1)+(an2+an3));
            float p = fmaxf(((am0+am1)+(am2+am3)) + l1b, 0.f) * l1w2v;
            #pragma unroll
            for (int off = 32; off > 0; off >>= 1)
                p += __shfl_xor(p, off);                 // all lanes get the sum
            float an = p + l1b2c;
            bool cond = (alpha - gam) >= 0.f;
            alpha = r ? (cond ? an : alpha) : (cond ? alpha : an);
            if (j == 0) out_alpha[b * Sn + t] = alpha;
        }
    } else {
        // ======== C3 chain (own-row, redundant per chunk) + forward-fill ========
        const int fb    = bid - GRU_BLOCKS;
        const int b     = fb >> 2;
        const int chunk = fb & 3;
        if (tid < Sn) {
            gam_lds[tid] = D_w[d_seq[b*Sn + tid]];
            r_lds[tid]   = r_seq[b*Sn + tid];
            c3_lds[tid]  = c3_seq[b*Sn + tid];
        }
        // collapsed mlp2 constants
        if (tid < 64) {
            const float* row = l2_w1 + (size_t)tid * 192;
            float a2=0.f, b2=0.f, c0=0.f, c1=0.f;
            for (int k = 0; k < 64; ++k) {
                a2 += row[k]       * v_c3[k];
                b2 += row[64 + k]  * v_d[k];
                c0 += row[128 + k] * R_w[k];
                c1 += row[128 + k] * R_w[64 + k];
            }
            wsA[tid]  = a2;
            wsB[tid]  = b2;
            wsC0[tid] = c0 + l2_b1[tid];
            wsC1[tid] = c1 + l2_b1[tid];
            wsW2[tid] = l2_w2[tid];
        }
        if (tid == 0) l2b2_sh = l2_b2[0];
        __syncthreads();
        if (tid < Sn) {
            int c = c3_lds[tid];
            int s = -1;
            for (int u = tid + 1; u < Sn; ++u)
                if (c3_lds[u] == c) { s = u; break; }
            succ_lds[tid] = s;
            int rt = 1;
            for (int u = 0; u < tid; ++u)
                if (c3_lds[u] == c) { rt = 0; break; }
            root_lds[tid] = rt;
        }
        __syncthreads();
        {
            const int g  = tid >> 4;
            const int l  = tid & 15;
            const int j0 = l * 4;
            float A0=wsA[j0],  A1=wsA[j0+1],  A2=wsA[j0+2],  A3=wsA[j0+3];
            float B0=wsB[j0],  B1=wsB[j0+1],  B2=wsB[j0+2],  B3=wsB[j0+3];
            float C00=wsC0[j0],C01=wsC0[j0+1],C02=wsC0[j0+2],C03=wsC0[j0+3];
            float C10=wsC1[j0],C11=wsC1[j0+1],C12=wsC1[j0+2],C13=wsC1[j0+3];
            float W0=wsW2[j0], W1=wsW2[j0+1], W2v=wsW2[j0+2],W3=wsW2[j0+3];
            float l2b2 = l2b2_sh;
            for (int t0 = g; t0 < Sn; t0 += 16) {
                if (!root_lds[t0]) continue;
                float beta = 0.f;
                int t = t0;
                while (t >= 0) {
                    float gam = gam_lds[t];
                    int   r   = r_lds[t];
                    float s = W0*fmaxf(A0*beta + B0*gam + (r ? C10 : C00), 0.f)
                            + W1*fmaxf(A1*beta + B1*gam + (r ? C11 : C01), 0.f)
                            + W2v*fmaxf(A2*beta + B2*gam + (r ? C12 : C02), 0.f)
                            + W3*fmaxf(A3*beta + B3*gam + (r ? C13 : C03), 0.f);
                    s += __shfl_xor(s, 1, 16);
                    s += __shfl_xor(s, 2, 16);
                    s += __shfl_xor(s, 4, 16);
                    s += __shfl_xor(s, 8, 16);
                    beta = s + l2b2;
                    if (l == 0) val_lds[t] = beta;
                    t = succ_lds[t];
                }
            }
        }
        __syncthreads();
        // 64B-aligned chunks: 1024,1024,1024,928 cols
        const int width = (chunk < 3) ? 256 : 232;       // threads (x4 cols)
        if (tid < width) {
            const int col = chunk * 1024 + tid * 4;
            float4 curv = make_float4(0.f, 0.f, 0.f, 0.f);
            float* outp = out_c3 + (size_t)b * Sn * NC3n + col;
            for (int t = 0; t < Sn; ++t) {
                int d = c3_lds[t] - col;
                if ((unsigned)d < 4u) {
                    float v = val_lds[t];
                    curv.x = (d == 0) ? v : curv.x;
                    curv.y = (d == 1) ? v : curv.y;
                    curv.z = (d == 2) ? v : curv.z;
                    curv.w = (d == 3) ? v : curv.w;
                }
                *(float4*)outp = curv;
                outp += NC3n;
            }
        }
    }
}

extern "C" void kernel_launch(void* const* d_in, const int* in_sizes, int n_in,
                              void* d_out, int out_size, void* d_ws, size_t ws_size,
                              hipStream_t stream)
{
    const int*   c3_seq = (const int*)  d_in[0];
    const int*   d_seq  = (const int*)  d_in[1];
    const int*   r_seq  = (const int*)  d_in[2];
    const float* v_c3   = (const float*)d_in[3];
    const float* D_w    = (const float*)d_in[4];
    const float* v_d    = (const float*)d_in[5];
    const float* R_w    = (const float*)d_in[6];
    const float* W_ih   = (const float*)d_in[7];
    const float* W_hh   = (const float*)d_in[8];
    const float* b_ih   = (const float*)d_in[9];
    const float* b_hh   = (const float*)d_in[10];
    const float* l1_w1  = (const float*)d_in[11];
    const float* l1_b1  = (const float*)d_in[12];
    const float* l1_w2  = (const float*)d_in[13];
    const float* l1_b2  = (const float*)d_in[14];
    const float* l2_w1  = (const float*)d_in[15];
    const float* l2_b1  = (const float*)d_in[16];
    const float* l2_w2  = (const float*)d_in[17];
    const float* l2_b2  = (const float*)d_in[18];

    float* out_alpha = (float*)d_out;
    float* out_h     = out_alpha + Bn*Sn;
    float* out_c3    = out_h + (size_t)Bn*Sn*64;

    fused_kernel<<<GRU_BLOCKS + FILL_BLOCKS, 256, 0, stream>>>(
        c3_seq, d_seq, r_seq, v_c3, D_w, v_d, R_w, W_ih, W_hh, b_ih, b_hh,
        l1_w1, l1_b1, l1_w2, l1_b2, l2_w1, l2_b1, l2_w2, l2_b2,
        out_alpha, out_h, out_c3);
}